// Round 3
// baseline (176.286 us; speedup 1.0000x reference)
//
#include <hip/hip_runtime.h>
#include <cstdint>
#include <cstddef>

#define B 4
#define N 16
#define V 32
#define HW 25600
#define TOPK 7
#define CA 256
#define NCA (HW / CA)   // 100
#define CC 128
#define NCC (HW / CC)   // 200

__device__ __forceinline__ bool better(float av, int ai, float bv, int bi) {
    return (av > bv) || (av == bv && ai < bi);
}

// ---------------- kA: per-(b,chunk) stats for ALL 16 instances ----------------
__global__ __launch_bounds__(256) void kA(
    const float* __restrict__ pred, const float* __restrict__ feat,
    const float* __restrict__ gt,
    float* __restrict__ ms_part, float* __restrict__ cs_part,
    float* __restrict__ cand_val, int* __restrict__ cand_idx) {
    int blk = blockIdx.x;             // b*NCA + ch
    int b = blk / NCA, ch = blk % NCA;
    int c0 = ch * CA;
    int tid = threadIdx.x;

    __shared__ float f_lds[V][CA + 1];     // stride 257: odd -> 2-way-free column reads
    __shared__ float g_lds[N][CA + 1];
    __shared__ float fs_lds[CA];
    __shared__ float p_lds[CA];

    const float* fb = feat + (size_t)b * V * HW + c0;
    const float* gb = gt + (size_t)b * N * HW + c0;

    // stage feat (8192 floats), gt (4096), pred (256) — scalar, coalesced, conflict-free
#pragma unroll
    for (int k = 0; k < 32; ++k) {
        int q = tid + 256 * k;
        int v = q >> 8, p = q & 255;
        f_lds[v][p] = fb[(size_t)v * HW + p];
    }
#pragma unroll
    for (int k = 0; k < 16; ++k) {
        int q = tid + 256 * k;
        int nn = q >> 8, p = q & 255;
        g_lds[nn][p] = gb[(size_t)nn * HW + p];
    }
    p_lds[tid] = pred[(size_t)b * HW + c0 + tid];
    __syncthreads();

    // fs[p] = sum_v feat^2
    {
        float fs = 0.f;
#pragma unroll
        for (int v = 0; v < V; ++v) {
            float f = f_lds[v][tid];
            fs = fmaf(f, f, fs);
        }
        fs_lds[tid] = fs;
    }
    __syncthreads();

    // main outer-product: ms[n][v] partials; thread = (ng wave, vg, ps)
    {
        int ng = tid >> 6, vg = (tid >> 4) & 3, ps = tid & 15;
        float acc[4][8];
#pragma unroll
        for (int i = 0; i < 4; ++i)
#pragma unroll
            for (int j = 0; j < 8; ++j) acc[i][j] = 0.f;

        for (int it = 0; it < 16; ++it) {
            int p = ps + 16 * it;
            float gv[4], fv[8];
#pragma unroll
            for (int i = 0; i < 4; ++i) gv[i] = g_lds[ng * 4 + i][p];
#pragma unroll
            for (int j = 0; j < 8; ++j) fv[j] = f_lds[vg * 8 + j][p];
#pragma unroll
            for (int i = 0; i < 4; ++i)
#pragma unroll
                for (int j = 0; j < 8; ++j) acc[i][j] = fmaf(gv[i], fv[j], acc[i][j]);
        }
        // all-reduce over ps (low 4 lane bits)
#pragma unroll
        for (int m = 1; m <= 8; m <<= 1)
#pragma unroll
            for (int i = 0; i < 4; ++i)
#pragma unroll
                for (int j = 0; j < 8; ++j) acc[i][j] += __shfl_xor(acc[i][j], m);
        // each ps lane stores 2 of the 32 values
        int fi0 = ps * 2;
#pragma unroll
        for (int u = 0; u < 2; ++u) {
            int fi = fi0 + u;
            int i = fi >> 3, j = fi & 7;
            ms_part[(size_t)blk * 512 + (ng * 4 + i) * 32 + vg * 8 + j] = acc[i][j];
        }
    }

    // per-(n,s): cnt, s2 = sum gt*fs, chunk top-7
    {
        int n = tid >> 4, s = tid & 15;
        float tv[TOPK]; int ti[TOPK];
#pragma unroll
        for (int j = 0; j < TOPK; ++j) { tv[j] = -INFINITY; ti[j] = 0x7fffffff; }
        float cnt = 0.f, s2 = 0.f;
#pragma unroll
        for (int k = 0; k < 16; ++k) {
            int p = s + 16 * k;
            float g = g_lds[n][p];
            float c = p_lds[p] * g;
            cnt += g;
            s2 = fmaf(g, fs_lds[p], s2);
            int pi = c0 + p;
            if (better(c, pi, tv[TOPK - 1], ti[TOPK - 1])) {
                tv[TOPK - 1] = c; ti[TOPK - 1] = pi;
#pragma unroll
                for (int j = TOPK - 2; j >= 0; --j) {
                    if (better(tv[j + 1], ti[j + 1], tv[j], ti[j])) {
                        float fv = tv[j]; int fi = ti[j];
                        tv[j] = tv[j + 1]; ti[j] = ti[j + 1];
                        tv[j + 1] = fv; ti[j + 1] = fi;
                    }
                }
            }
        }
#pragma unroll
        for (int m = 1; m <= 8; m <<= 1) {
            cnt += __shfl_xor(cnt, m);
            s2 += __shfl_xor(s2, m);
        }
        if (s == 0) {
            cs_part[(size_t)blk * 32 + n] = cnt;
            cs_part[(size_t)blk * 32 + 16 + n] = s2;
        }
        int cb = blk * 112 + n * 7;
#pragma unroll
        for (int r = 0; r < TOPK; ++r) {
            float bv = tv[0]; int bi = ti[0];
#pragma unroll
            for (int m = 1; m <= 8; m <<= 1) {
                float ov = __shfl_xor(bv, m);
                int oi = __shfl_xor(bi, m);
                if (better(ov, oi, bv, bi)) { bv = ov; bi = oi; }
            }
            if (ti[0] == bi) {
#pragma unroll
                for (int j = 0; j < TOPK - 1; ++j) { tv[j] = tv[j + 1]; ti[j] = ti[j + 1]; }
                tv[TOPK - 1] = -INFINITY; ti[TOPK - 1] = 0x7fffffff;
            }
            if (s == 0) { cand_val[cb + r] = bv; cand_idx[cb + r] = bi; }
        }
    }
}

// ---------------- kB: finalize stats, merge top-7, build E ----------------
__global__ __launch_bounds__(64) void kB(
    const float* __restrict__ feat, const int* __restrict__ valid,
    const float* __restrict__ ms_part, const float* __restrict__ cs_part,
    const float* __restrict__ cand_val, const int* __restrict__ cand_idx,
    float* __restrict__ Ebuf, float* __restrict__ cntbuf, float* __restrict__ out) {
    int bn = blockIdx.x;
    int b = bn >> 4, n = bn & 15;
    int lane = threadIdx.x;

    float num = 0.f;
    if (lane < V) {
        for (int ch = 0; ch < NCA; ++ch)
            num += ms_part[(size_t)(b * NCA + ch) * 512 + n * 32 + lane];
    }
    float cs = 0.f;
    if (lane >= 32) {
        int base = (lane < 48) ? 0 : 16;
        int s = lane & 15;
        for (int ch = s; ch < NCA; ch += 16)
            cs += cs_part[(size_t)(b * NCA + ch) * 32 + base + n];
    }
#pragma unroll
    for (int m = 1; m <= 8; m <<= 1) cs += __shfl_xor(cs, m);
    float cnt = __shfl(cs, 32);
    float s2 = __shfl(cs, 48);
    float pix = fmaxf(cnt, 1.0f);
    float mu = (lane < V) ? num / pix : 0.f;
    float msq = mu * mu;
#pragma unroll
    for (int m = 1; m <= 32; m <<= 1) msq += __shfl_xor(msq, m);
    if (lane == 0) {
        atomicAdd(out + 2, (s2 / pix - msq) * (float)valid[bn]);
        cntbuf[bn] = cnt;
    }
    if (lane < V) Ebuf[bn * 256 + lane] = mu;

    // merge 700 candidates -> top 7; gather E rows 1..7
    float tv[TOPK]; int ti[TOPK];
#pragma unroll
    for (int j = 0; j < TOPK; ++j) { tv[j] = -INFINITY; ti[j] = 0x7fffffff; }
#pragma unroll
    for (int k = 0; k < 11; ++k) {
        int t = lane + 64 * k;
        if (t < NCA * TOPK) {
            int ch = t / 7, j = t % 7;
            float cv = cand_val[(size_t)(b * NCA + ch) * 112 + n * 7 + j];
            int ci = cand_idx[(size_t)(b * NCA + ch) * 112 + n * 7 + j];
            if (better(cv, ci, tv[TOPK - 1], ti[TOPK - 1])) {
                tv[TOPK - 1] = cv; ti[TOPK - 1] = ci;
#pragma unroll
                for (int q = TOPK - 2; q >= 0; --q) {
                    if (better(tv[q + 1], ti[q + 1], tv[q], ti[q])) {
                        float fv = tv[q]; int fi = ti[q];
                        tv[q] = tv[q + 1]; ti[q] = ti[q + 1];
                        tv[q + 1] = fv; ti[q + 1] = fi;
                    }
                }
            }
        }
    }
#pragma unroll
    for (int r = 0; r < TOPK; ++r) {
        float bv = tv[0]; int bi = ti[0];
#pragma unroll
        for (int m = 1; m <= 32; m <<= 1) {
            float ov = __shfl_xor(bv, m);
            int oi = __shfl_xor(bi, m);
            if (better(ov, oi, bv, bi)) { bv = ov; bi = oi; }
        }
        if (ti[0] == bi) {
#pragma unroll
            for (int j = 0; j < TOPK - 1; ++j) { tv[j] = tv[j + 1]; ti[j] = ti[j + 1]; }
            tv[TOPK - 1] = -INFINITY; ti[TOPK - 1] = 0x7fffffff;
        }
        if (lane < V)
            Ebuf[bn * 256 + (r + 1) * 32 + lane] = feat[((size_t)b * V + lane) * HW + bi];
    }
}

// ---------------- kC: per-(b,chunk) sigmoid-GEMM dice partials ----------------
__global__ __launch_bounds__(256) void kC(
    const float* __restrict__ feat, const float* __restrict__ gt,
    const float* __restrict__ Ebuf, float* __restrict__ sums) {
    int blk = blockIdx.x;
    int b = blk / NCC, ch = blk % NCC;
    int c0 = ch * CC;
    int tid = threadIdx.x;
    int n = tid >> 4, pg = tid & 15;

    __shared__ float f_lds[V][CC + 4];     // stride 132 (16B-aligned rows)
    __shared__ float e_lds[128 * 33];
    __shared__ float g_lds[N][CC + 4];

    const float* fb = feat + (size_t)b * V * HW + c0;
    const float* gb = gt + (size_t)b * N * HW + c0;
    const float* eb = Ebuf + (size_t)b * 16 * 256;
#pragma unroll
    for (int k = 0; k < 16; ++k) {
        int q = tid + 256 * k;
        int v = q >> 7, p = q & 127;
        f_lds[v][p] = fb[(size_t)v * HW + p];
    }
#pragma unroll
    for (int k = 0; k < 8; ++k) {
        int q = tid + 256 * k;
        int nn = q >> 7, p = q & 127;
        g_lds[nn][p] = gb[(size_t)nn * HW + p];
    }
#pragma unroll
    for (int k = 0; k < 16; ++k) {
        int q = tid + 256 * k;
        int nr = q >> 5, v = q & 31;
        e_lds[nr * 33 + v] = eb[q];
    }
    __syncthreads();

    float acc[8][8];
#pragma unroll
    for (int r = 0; r < 8; ++r)
#pragma unroll
        for (int j = 0; j < 8; ++j) acc[r][j] = 0.f;

    int p0 = pg * 4;
    for (int v = 0; v < V; ++v) {
        float4 fa = *reinterpret_cast<const float4*>(&f_lds[v][p0]);
        float4 fc = *reinterpret_cast<const float4*>(&f_lds[v][p0 + 64]);
        float e[8];
#pragma unroll
        for (int r = 0; r < 8; ++r) e[r] = e_lds[(n * 8 + r) * 33 + v];
#pragma unroll
        for (int r = 0; r < 8; ++r) {
            acc[r][0] = fmaf(e[r], fa.x, acc[r][0]);
            acc[r][1] = fmaf(e[r], fa.y, acc[r][1]);
            acc[r][2] = fmaf(e[r], fa.z, acc[r][2]);
            acc[r][3] = fmaf(e[r], fa.w, acc[r][3]);
            acc[r][4] = fmaf(e[r], fc.x, acc[r][4]);
            acc[r][5] = fmaf(e[r], fc.y, acc[r][5]);
            acc[r][6] = fmaf(e[r], fc.z, acc[r][6]);
            acc[r][7] = fmaf(e[r], fc.w, acc[r][7]);
        }
    }

    float4 ga = *reinterpret_cast<const float4*>(&g_lds[n][p0]);
    float4 gc = *reinterpret_cast<const float4*>(&g_lds[n][p0 + 64]);
    float g[8] = { ga.x, ga.y, ga.z, ga.w, gc.x, gc.y, gc.z, gc.w };
    float p2[8], tp[8];
#pragma unroll
    for (int r = 0; r < 8; ++r) { p2[r] = 0.f; tp[r] = 0.f; }
#pragma unroll
    for (int r = 0; r < 8; ++r)
#pragma unroll
        for (int j = 0; j < 8; ++j) {
            float sg = 1.f / (1.f + __expf(-acc[r][j]));
            p2[r] = fmaf(sg, sg, p2[r]);
            tp[r] = fmaf(g[j], sg, tp[r]);
        }
#pragma unroll
    for (int m = 1; m <= 8; m <<= 1)
#pragma unroll
        for (int r = 0; r < 8; ++r) {
            p2[r] += __shfl_xor(p2[r], m);
            tp[r] += __shfl_xor(tp[r], m);
        }
    if (pg == 0) {
        int base = (b * 16 + n) * 16;
#pragma unroll
        for (int r = 0; r < 8; ++r) {
            atomicAdd(sums + base + r * 2, p2[r]);
            atomicAdd(sums + base + r * 2 + 1, tp[r]);
        }
    }
}

// ---------------- kD: fold dice sums into losses ----------------
__global__ void kD(const float* __restrict__ sums, const float* __restrict__ cntbuf,
                   const int* __restrict__ valid, float* __restrict__ out) {
    int bn = threadIdx.x;   // 64 threads
    float vw = (float)valid[bn];
    float cnt = cntbuf[bn];
    float mloss = 0.f, iloss = 0.f;
#pragma unroll
    for (int r = 0; r < 8; ++r) {
        float p2 = sums[bn * 16 + r * 2];
        float tp = sums[bn * 16 + r * 2 + 1];
        float denom = fmaxf(p2 + cnt, 1e-8f);
        float dice = 1.f - 2.f * tp / denom;
        if (r == 0) mloss = dice * vw;
        else iloss += dice * vw;
    }
    atomicAdd(out + 0, mloss);
    atomicAdd(out + 1, iloss);
}

extern "C" void kernel_launch(void* const* d_in, const int* in_sizes, int n_in,
                              void* d_out, int out_size, void* d_ws, size_t ws_size,
                              hipStream_t stream) {
    const float* pred = (const float*)d_in[0];
    const float* feat = (const float*)d_in[1];
    const float* gtin = (const float*)d_in[2];
    const int* valid  = (const int*)d_in[3];
    float* out = (float*)d_out;

    char* ws = (char*)d_ws;
    float* ms_part  = (float*)(ws);                 // 400*512*4  = 819200
    float* cs_part  = (float*)(ws + 819200);        // 400*32*4   =  51200
    float* cand_val = (float*)(ws + 870400);        // 400*112*4  = 179200
    int*   cand_idx = (int*)  (ws + 1049600);       // 179200
    float* Ebuf     = (float*)(ws + 1228800);       // 64*256*4   =  65536
    float* cntbuf   = (float*)(ws + 1294336);       // 256
    float* sums     = (float*)(ws + 1294592);       // 64*16*4    =   4096

    hipMemsetAsync(out, 0, 3 * sizeof(float), stream);
    hipMemsetAsync(sums, 0, 64 * 16 * sizeof(float), stream);

    kA<<<B * NCA, 256, 0, stream>>>(pred, feat, gtin, ms_part, cs_part, cand_val, cand_idx);
    kB<<<B * N, 64, 0, stream>>>(feat, valid, ms_part, cs_part, cand_val, cand_idx,
                                 Ebuf, cntbuf, out);
    kC<<<B * NCC, 256, 0, stream>>>(feat, gtin, Ebuf, sums);
    kD<<<1, 64, 0, stream>>>(sums, cntbuf, valid, out);
}